// Round 1
// baseline (474.175 us; speedup 1.0000x reference)
//
#include <hip/hip_runtime.h>
#include <math.h>

#define D 128
#define BN_EPS 1e-3f
#define L2_EPS 1e-12f

// ---------------------------------------------------------------------------
// row_ptr[i] = lower_bound(rows, i) for i in [0, n]; rows is sorted ascending.
// ---------------------------------------------------------------------------
__global__ void build_row_ptr_kernel(const int* __restrict__ rows,
                                     int* __restrict__ row_ptr, int n, int e) {
  int i = blockIdx.x * blockDim.x + threadIdx.x;
  if (i > n) return;
  int lo = 0, hi = e;
  while (lo < hi) {
    int mid = (lo + hi) >> 1;
    if (rows[mid] < i) lo = mid + 1; else hi = mid;
  }
  row_ptr[i] = lo;
}

// ---------------------------------------------------------------------------
// Fold BN1 into W1:  Ws[k][j] = s1[k] * W1[k][j],  s1 = gamma*rsqrt(var+eps)
// ---------------------------------------------------------------------------
__global__ void scale_w_kernel(const float* __restrict__ W,
                               const float* __restrict__ gamma,
                               const float* __restrict__ var,
                               float* __restrict__ Ws) {
  int k = blockIdx.x, j = threadIdx.x;
  float s = gamma[k] * rsqrtf(var[k] + BN_EPS);
  Ws[k * D + j] = s * W[k * D + j];
}

// bnb[j] = sum_k (beta[k] - mean[k]*s[k]) * W[k][j]   (row-independent bias)
__global__ void bn_bias_kernel(const float* __restrict__ W,
                               const float* __restrict__ gamma,
                               const float* __restrict__ beta,
                               const float* __restrict__ mean,
                               const float* __restrict__ var,
                               float* __restrict__ outb) {
  int j = threadIdx.x;
  float acc = 0.f;
  for (int k = 0; k < D; ++k) {
    float s = gamma[k] * rsqrtf(var[k] + BN_EPS);
    float sh = beta[k] - mean[k] * s;
    acc += sh * W[k * D + j];
  }
  outb[j] = acc;
}

// ---------------------------------------------------------------------------
// C[M][128] = A[M][128] @ B[128][128] + bias[128]
// 64 rows/block, 256 threads. A staged transposed (AsT[k][r], 32KB, b128
// reads conflict-free), B staged in two 64-k halves (32KB) -> 64KB LDS total
// (2 blocks/CU). 4x8 register micro-tile: 128 FMA per 12 LDS reads.
// ---------------------------------------------------------------------------
__global__ __launch_bounds__(256) void gemm_nn128_kernel(
    const float* __restrict__ A, const float* __restrict__ B,
    const float* __restrict__ bias, float* __restrict__ C, int M) {
  __shared__ float AsT[D * 64];   // [k][r]
  __shared__ float Bs[64 * D];    // [k_local][j]
  const int tid = threadIdx.x;
  const int row0 = blockIdx.x * 64;

  // Stage A transposed: 2048 float4, 8 per thread.
#pragma unroll
  for (int i = 0; i < 8; ++i) {
    int idx = i * 256 + tid;
    int r = idx >> 5, c4 = idx & 31;
    float4 v = make_float4(0.f, 0.f, 0.f, 0.f);
    if (row0 + r < M) v = reinterpret_cast<const float4*>(A)[(size_t)(row0 + r) * 32 + c4];
    AsT[(c4 * 4 + 0) * 64 + r] = v.x;
    AsT[(c4 * 4 + 1) * 64 + r] = v.y;
    AsT[(c4 * 4 + 2) * 64 + r] = v.z;
    AsT[(c4 * 4 + 3) * 64 + r] = v.w;
  }

  float acc[4][8];
#pragma unroll
  for (int i = 0; i < 4; ++i)
#pragma unroll
    for (int j = 0; j < 8; ++j) acc[i][j] = 0.f;

  const int tx = tid & 15, ty = tid >> 4;  // thread -> 4 rows (ty*4+i), 8 cols (tx*8+j)

  for (int kh = 0; kh < 2; ++kh) {
    __syncthreads();  // (kh=1) everyone done reading Bs; harmless at kh=0
#pragma unroll
    for (int i = 0; i < 8; ++i) {
      int idx = i * 256 + tid;
      reinterpret_cast<float4*>(Bs)[idx] =
          reinterpret_cast<const float4*>(B)[kh * 2048 + idx];
    }
    __syncthreads();  // AsT + Bs ready

#pragma unroll 4
    for (int k = 0; k < 64; k += 4) {
#pragma unroll
      for (int kk = 0; kk < 4; ++kk) {
        const int kg = kh * 64 + k + kk;
        const float4 av = *reinterpret_cast<const float4*>(&AsT[kg * 64 + ty * 4]);
        const float4 b0 = *reinterpret_cast<const float4*>(&Bs[(k + kk) * D + tx * 8]);
        const float4 b1 = *reinterpret_cast<const float4*>(&Bs[(k + kk) * D + tx * 8 + 4]);
        float bv[8] = {b0.x, b0.y, b0.z, b0.w, b1.x, b1.y, b1.z, b1.w};
#pragma unroll
        for (int j = 0; j < 8; ++j) {
          acc[0][j] += av.x * bv[j];
          acc[1][j] += av.y * bv[j];
          acc[2][j] += av.z * bv[j];
          acc[3][j] += av.w * bv[j];
        }
      }
    }
  }

  float bj[8];
#pragma unroll
  for (int j = 0; j < 8; ++j) bj[j] = bias[tx * 8 + j];
#pragma unroll
  for (int i = 0; i < 4; ++i) {
    int gr = row0 + ty * 4 + i;
    if (gr < M) {
      float4 o0 = make_float4(acc[i][0] + bj[0], acc[i][1] + bj[1],
                              acc[i][2] + bj[2], acc[i][3] + bj[3]);
      float4 o1 = make_float4(acc[i][4] + bj[4], acc[i][5] + bj[5],
                              acc[i][6] + bj[6], acc[i][7] + bj[7]);
      reinterpret_cast<float4*>(C)[(size_t)gr * 32 + tx * 2] = o0;
      reinterpret_cast<float4*>(C)[(size_t)gr * 32 + tx * 2 + 1] = o1;
    }
  }
}

// ---------------------------------------------------------------------------
// SpMM 1: y1[r] = tanh( sum_e adj[e] * hW[cols[e]] + b1 ).
// rows sorted -> CSR pull, no atomics. One block per row, lane = feature dim.
// ---------------------------------------------------------------------------
__global__ __launch_bounds__(128) void spmm1_kernel(
    const float* __restrict__ hW, const int* __restrict__ row_ptr,
    const int* __restrict__ cols, const float* __restrict__ vals,
    const float* __restrict__ b1, float* __restrict__ y1) {
  int r = blockIdx.x, d = threadIdx.x;
  int e0 = row_ptr[r], e1 = row_ptr[r + 1];
  float acc = 0.f;
  for (int e = e0; e < e1; ++e)
    acc += vals[e] * hW[(size_t)cols[e] * D + d];
  y1[(size_t)r * D + d] = tanhf(acc + b1[d]);
}

// ---------------------------------------------------------------------------
// SpMM 2 + self term:  t[r] = sum_e ev[e]*BN2(y1[cols[e]]) + BN2(y1[r])*(ck[r]+1)
// ev[e] = adj[e] / (relc[rel[e]] + 1).  BN2 applied on the fly (affine per lane).
// ---------------------------------------------------------------------------
__global__ __launch_bounds__(128) void spmm2_kernel(
    const float* __restrict__ y1, const int* __restrict__ row_ptr,
    const int* __restrict__ cols, const float* __restrict__ vals,
    const int* __restrict__ rel_ids, const float* __restrict__ relc,
    const float* __restrict__ gamma2, const float* __restrict__ beta2,
    const float* __restrict__ mean2, const float* __restrict__ var2,
    const float* __restrict__ ck, float* __restrict__ t) {
  int r = blockIdx.x, d = threadIdx.x;
  float s = gamma2[d] * rsqrtf(var2[d] + BN_EPS);
  float sh = beta2[d] - mean2[d] * s;
  int e0 = row_ptr[r], e1 = row_ptr[r + 1];
  float acc = 0.f;
  for (int e = e0; e < e1; ++e) {
    float ev = vals[e] / (relc[rel_ids[e]] + 1.0f);
    acc += ev * (y1[(size_t)cols[e] * D + d] * s + sh);
  }
  float self = (y1[(size_t)r * D + d] * s + sh) * (ck[r] + 1.0f);
  t[(size_t)r * D + d] = acc + self;
}

// ---------------------------------------------------------------------------
// Final: out[r] = l2n( [l2n(x_r), l2n(y1_r), l2n(y2_r)] ), 384 cols per row.
// ---------------------------------------------------------------------------
__global__ __launch_bounds__(128) void finalize_kernel(
    const float* __restrict__ x, const float* __restrict__ y1,
    const float* __restrict__ y2, float* __restrict__ out) {
  int r = blockIdx.x, d = threadIdx.x;
  float vx = x[(size_t)r * D + d];
  float v1 = y1[(size_t)r * D + d];
  float v2 = y2[(size_t)r * D + d];
  float s0 = vx * vx, s1 = v1 * v1, s2 = v2 * v2;
#pragma unroll
  for (int m = 1; m < 64; m <<= 1) {
    s0 += __shfl_xor(s0, m);
    s1 += __shfl_xor(s1, m);
    s2 += __shfl_xor(s2, m);
  }
  __shared__ float sw[2][3];
  int w = d >> 6;
  if ((d & 63) == 0) { sw[w][0] = s0; sw[w][1] = s1; sw[w][2] = s2; }
  __syncthreads();
  s0 = sw[0][0] + sw[1][0];
  s1 = sw[0][1] + sw[1][1];
  s2 = sw[0][2] + sw[1][2];
  float i0 = 1.0f / sqrtf(fmaxf(s0, L2_EPS));
  float i1 = 1.0f / sqrtf(fmaxf(s1, L2_EPS));
  float i2 = 1.0f / sqrtf(fmaxf(s2, L2_EPS));
  // squared norm of the concatenation of the three normalized parts
  float tot = s0 * i0 * i0 + s1 * i1 * i1 + s2 * i2 * i2;
  float sc = 1.0f / sqrtf(fmaxf(tot, L2_EPS));
  out[(size_t)r * 384 + d] = vx * i0 * sc;
  out[(size_t)r * 384 + 128 + d] = v1 * i1 * sc;
  out[(size_t)r * 384 + 256 + d] = v2 * i2 * sc;
}

// ---------------------------------------------------------------------------
// Workspace layout (floats):
//   [0, nd)        hW   (reused as y2 after spmm2 no longer needs it)
//   [nd, 2nd)      y1
//   [2nd, 3nd)     t = agg + self
//   [3nd, +16384)  W1s (BN1-folded W1)
//   [.., +128)     bnb (BN1-folded bias)
//   then (int*)    row_ptr[n+1]
// Total ~77.1 MB.
// ---------------------------------------------------------------------------
extern "C" void kernel_launch(void* const* d_in, const int* in_sizes, int n_in,
                              void* d_out, int out_size, void* d_ws, size_t ws_size,
                              hipStream_t stream) {
  const float* x      = (const float*)d_in[0];
  const int*   rows   = (const int*)d_in[1];
  const int*   cols   = (const int*)d_in[2];
  const float* adj    = (const float*)d_in[3];
  const int*   rel    = (const int*)d_in[4];
  const float* gamma1 = (const float*)d_in[5];
  const float* beta1  = (const float*)d_in[6];
  const float* mean1  = (const float*)d_in[7];
  const float* var1   = (const float*)d_in[8];
  const float* W1     = (const float*)d_in[9];
  const float* b1     = (const float*)d_in[10];
  const float* gamma2 = (const float*)d_in[11];
  const float* beta2  = (const float*)d_in[12];
  const float* mean2  = (const float*)d_in[13];
  const float* var2   = (const float*)d_in[14];
  const float* relc   = (const float*)d_in[15];
  const float* ck     = (const float*)d_in[16];
  const float* Wd     = (const float*)d_in[17];
  const float* bd     = (const float*)d_in[18];
  float* out = (float*)d_out;

  const int n = in_sizes[0] / D;
  const int e = in_sizes[1];

  float* ws = (float*)d_ws;
  size_t nd = (size_t)n * D;
  float* hW  = ws;
  float* y1  = ws + nd;
  float* t   = ws + 2 * nd;
  float* W1s = ws + 3 * nd;
  float* bnb = W1s + D * D;
  int* row_ptr = (int*)(bnb + D);

  build_row_ptr_kernel<<<(n + 1 + 255) / 256, 256, 0, stream>>>(rows, row_ptr, n, e);
  scale_w_kernel<<<D, D, 0, stream>>>(W1, gamma1, var1, W1s);
  bn_bias_kernel<<<1, D, 0, stream>>>(W1, gamma1, beta1, mean1, var1, bnb);

  int gblocks = (n + 63) / 64;
  gemm_nn128_kernel<<<gblocks, 256, 0, stream>>>(x, W1s, bnb, hW, n);
  spmm1_kernel<<<n, D, 0, stream>>>(hW, row_ptr, cols, adj, b1, y1);
  spmm2_kernel<<<n, D, 0, stream>>>(y1, row_ptr, cols, adj, rel, relc,
                                    gamma2, beta2, mean2, var2, ck, t);
  float* y2 = hW;  // hW dead after spmm1; reuse
  gemm_nn128_kernel<<<gblocks, 256, 0, stream>>>(t, Wd, bd, y2, n);
  finalize_kernel<<<n, D, 0, stream>>>(x, y1, y2, out);
}

// Round 2
// 408.938 us; speedup vs baseline: 1.1595x; 1.1595x over previous
//
#include <hip/hip_runtime.h>
#include <math.h>

#define D 128
#define BN_EPS 1e-3f
#define L2_EPS 1e-12f

typedef unsigned int uint;
typedef unsigned short ushort;

__device__ __forceinline__ ushort f2bf(float f) {
  uint u = __float_as_uint(f);
  uint r = (u + 0x7fffu + ((u >> 16) & 1u)) >> 16;
  return (ushort)r;
}
__device__ __forceinline__ float bf2f(ushort h) {
  return __uint_as_float(((uint)h) << 16);
}

// ---------------------------------------------------------------------------
// row_ptr[i] = lower_bound(rows, i); rows sorted ascending.
// ---------------------------------------------------------------------------
__global__ void build_row_ptr_kernel(const int* __restrict__ rows,
                                     int* __restrict__ row_ptr, int n, int e) {
  int i = blockIdx.x * blockDim.x + threadIdx.x;
  if (i > n) return;
  int lo = 0, hi = e;
  while (lo < hi) {
    int mid = (lo + hi) >> 1;
    if (rows[mid] < i) lo = mid + 1; else hi = mid;
  }
  row_ptr[i] = lo;
}

// Ws[k][j] = gamma[k]*rsqrt(var[k]+eps) * W[k][j]
__global__ void scale_w_kernel(const float* __restrict__ W,
                               const float* __restrict__ gamma,
                               const float* __restrict__ var,
                               float* __restrict__ Ws) {
  int k = blockIdx.x, j = threadIdx.x;
  float s = gamma[k] * rsqrtf(var[k] + BN_EPS);
  Ws[k * D + j] = s * W[k * D + j];
}

// outb[j] = sum_k (beta[k] - mean[k]*s[k]) * W[k][j]
__global__ void bn_bias_kernel(const float* __restrict__ W,
                               const float* __restrict__ gamma,
                               const float* __restrict__ beta,
                               const float* __restrict__ mean,
                               const float* __restrict__ var,
                               float* __restrict__ outb) {
  int j = threadIdx.x;
  float acc = 0.f;
  for (int k = 0; k < D; ++k) {
    float s = gamma[k] * rsqrtf(var[k] + BN_EPS);
    float sh = beta[k] - mean[k] * s;
    acc += sh * W[k * D + j];
  }
  outb[j] = acc;
}

// fp32 -> bf16 (RN), 4 elems/thread
__global__ void f32_to_bf16_kernel(const float* __restrict__ in,
                                   ushort* __restrict__ out, int n4) {
  int i = blockIdx.x * blockDim.x + threadIdx.x;
  if (i >= n4) return;
  float4 v = reinterpret_cast<const float4*>(in)[i];
  ushort4 o;
  o.x = f2bf(v.x); o.y = f2bf(v.y); o.z = f2bf(v.z); o.w = f2bf(v.w);
  reinterpret_cast<ushort4*>(out)[i] = o;
}

// ---------------------------------------------------------------------------
// SpMM (CSR pull, wave-per-row): agg[r] = sum_e w_e * src[cols[e]] (bf16 src),
// rowsum[r] = sum_e w_e.  REL: w_e = vals[e] / (relc[rel_ids[e]]+1).
// Lane l covers features 2l, 2l+1 via one uint load (256 B/edge coalesced).
// ---------------------------------------------------------------------------
template <bool REL>
__global__ __launch_bounds__(256) void spmm_bf16_kernel(
    const ushort* __restrict__ src, const int* __restrict__ row_ptr,
    const int* __restrict__ cols, const float* __restrict__ vals,
    const int* __restrict__ rel_ids, const float* __restrict__ relc,
    float* __restrict__ agg, float* __restrict__ rowsum, int n) {
  int wave = threadIdx.x >> 6;
  int lane = threadIdx.x & 63;
  int r = blockIdx.x * 4 + wave;
  if (r >= n) return;
  int e0 = row_ptr[r], e1 = row_ptr[r + 1];
  float a0 = 0.f, a1 = 0.f, b0 = 0.f, b1 = 0.f, ws = 0.f;
  int e = e0;
  for (; e + 2 <= e1; e += 2) {
    int c0 = cols[e], c1 = cols[e + 1];
    float w0 = vals[e], w1 = vals[e + 1];
    if (REL) {
      w0 /= (relc[rel_ids[e]] + 1.0f);
      w1 /= (relc[rel_ids[e + 1]] + 1.0f);
    }
    uint u0 = reinterpret_cast<const uint*>(src + (size_t)c0 * D)[lane];
    uint u1 = reinterpret_cast<const uint*>(src + (size_t)c1 * D)[lane];
    a0 = fmaf(w0, __uint_as_float(u0 << 16), a0);
    a1 = fmaf(w0, __uint_as_float(u0 & 0xffff0000u), a1);
    b0 = fmaf(w1, __uint_as_float(u1 << 16), b0);
    b1 = fmaf(w1, __uint_as_float(u1 & 0xffff0000u), b1);
    ws += w0 + w1;
  }
  if (e < e1) {
    int c0 = cols[e];
    float w0 = vals[e];
    if (REL) w0 /= (relc[rel_ids[e]] + 1.0f);
    uint u0 = reinterpret_cast<const uint*>(src + (size_t)c0 * D)[lane];
    a0 = fmaf(w0, __uint_as_float(u0 << 16), a0);
    a1 = fmaf(w0, __uint_as_float(u0 & 0xffff0000u), a1);
    ws += w0;
  }
  a0 += b0; a1 += b1;
  reinterpret_cast<float2*>(agg + (size_t)r * D)[lane] = make_float2(a0, a1);
  if (lane == 0) rowsum[r] = ws;
}

// ---------------------------------------------------------------------------
// GEMM1: y1 = tanh(agg @ W1s + rowsum1[r]*bnb + b1), bf16 output.
// 64 rows/block, 256 threads, AsT[k][r] + Bs staged, 4x8 micro-tile.
// ---------------------------------------------------------------------------
__global__ __launch_bounds__(256) void gemm1_kernel(
    const float* __restrict__ A, const float* __restrict__ B,
    const float* __restrict__ bnb, const float* __restrict__ b1,
    const float* __restrict__ rs1, ushort* __restrict__ y1, int M) {
  __shared__ float AsT[D * 64];
  __shared__ float Bs[64 * D];
  const int tid = threadIdx.x;
  const int row0 = blockIdx.x * 64;

#pragma unroll
  for (int i = 0; i < 8; ++i) {
    int idx = i * 256 + tid;
    int r = idx >> 5, c4 = idx & 31;
    float4 v = make_float4(0.f, 0.f, 0.f, 0.f);
    if (row0 + r < M) v = reinterpret_cast<const float4*>(A)[(size_t)(row0 + r) * 32 + c4];
    AsT[(c4 * 4 + 0) * 64 + r] = v.x;
    AsT[(c4 * 4 + 1) * 64 + r] = v.y;
    AsT[(c4 * 4 + 2) * 64 + r] = v.z;
    AsT[(c4 * 4 + 3) * 64 + r] = v.w;
  }

  float acc[4][8];
#pragma unroll
  for (int i = 0; i < 4; ++i)
#pragma unroll
    for (int j = 0; j < 8; ++j) acc[i][j] = 0.f;

  const int tx = tid & 15, ty = tid >> 4;

  for (int kh = 0; kh < 2; ++kh) {
    __syncthreads();
#pragma unroll
    for (int i = 0; i < 8; ++i) {
      int idx = i * 256 + tid;
      reinterpret_cast<float4*>(Bs)[idx] =
          reinterpret_cast<const float4*>(B)[kh * 2048 + idx];
    }
    __syncthreads();
#pragma unroll 4
    for (int k = 0; k < 64; k += 4) {
#pragma unroll
      for (int kk = 0; kk < 4; ++kk) {
        const int kg = kh * 64 + k + kk;
        const float4 av = *reinterpret_cast<const float4*>(&AsT[kg * 64 + ty * 4]);
        const float4 v0 = *reinterpret_cast<const float4*>(&Bs[(k + kk) * D + tx * 8]);
        const float4 v1 = *reinterpret_cast<const float4*>(&Bs[(k + kk) * D + tx * 8 + 4]);
        float bv[8] = {v0.x, v0.y, v0.z, v0.w, v1.x, v1.y, v1.z, v1.w};
#pragma unroll
        for (int j = 0; j < 8; ++j) {
          acc[0][j] += av.x * bv[j];
          acc[1][j] += av.y * bv[j];
          acc[2][j] += av.z * bv[j];
          acc[3][j] += av.w * bv[j];
        }
      }
    }
  }

  float cb[8], bb[8];
#pragma unroll
  for (int j = 0; j < 8; ++j) { cb[j] = bnb[tx * 8 + j]; bb[j] = b1[tx * 8 + j]; }
#pragma unroll
  for (int i = 0; i < 4; ++i) {
    int gr = row0 + ty * 4 + i;
    if (gr < M) {
      float rs = rs1[gr];
      uint4 pk;
      float t0 = tanhf(acc[i][0] + rs * cb[0] + bb[0]);
      float t1 = tanhf(acc[i][1] + rs * cb[1] + bb[1]);
      float t2 = tanhf(acc[i][2] + rs * cb[2] + bb[2]);
      float t3 = tanhf(acc[i][3] + rs * cb[3] + bb[3]);
      float t4 = tanhf(acc[i][4] + rs * cb[4] + bb[4]);
      float t5 = tanhf(acc[i][5] + rs * cb[5] + bb[5]);
      float t6 = tanhf(acc[i][6] + rs * cb[6] + bb[6]);
      float t7 = tanhf(acc[i][7] + rs * cb[7] + bb[7]);
      pk.x = (uint)f2bf(t0) | ((uint)f2bf(t1) << 16);
      pk.y = (uint)f2bf(t2) | ((uint)f2bf(t3) << 16);
      pk.z = (uint)f2bf(t4) | ((uint)f2bf(t5) << 16);
      pk.w = (uint)f2bf(t6) | ((uint)f2bf(t7) << 16);
      reinterpret_cast<uint4*>(y1 + (size_t)gr * D)[tx] = pk;
    }
  }
}

// ---------------------------------------------------------------------------
// GEMM2: y2 = (agg2 + y1*(ck+1)) @ Wds + (rowsum2[r]+ck[r]+1)*shd + bd
// A combined on the fly during staging; fp32 output.
// ---------------------------------------------------------------------------
__global__ __launch_bounds__(256) void gemm2_kernel(
    const float* __restrict__ A, const ushort* __restrict__ y1,
    const float* __restrict__ ck, const float* __restrict__ B,
    const float* __restrict__ shd, const float* __restrict__ bd,
    const float* __restrict__ rs2, float* __restrict__ y2, int M) {
  __shared__ float AsT[D * 64];
  __shared__ float Bs[64 * D];
  const int tid = threadIdx.x;
  const int row0 = blockIdx.x * 64;

#pragma unroll
  for (int i = 0; i < 8; ++i) {
    int idx = i * 256 + tid;
    int r = idx >> 5, c4 = idx & 31;
    float4 v = make_float4(0.f, 0.f, 0.f, 0.f);
    if (row0 + r < M) {
      v = reinterpret_cast<const float4*>(A)[(size_t)(row0 + r) * 32 + c4];
      ushort4 yv = reinterpret_cast<const ushort4*>(y1 + (size_t)(row0 + r) * D)[c4];
      float cp = ck[row0 + r] + 1.0f;
      v.x = fmaf(bf2f(yv.x), cp, v.x);
      v.y = fmaf(bf2f(yv.y), cp, v.y);
      v.z = fmaf(bf2f(yv.z), cp, v.z);
      v.w = fmaf(bf2f(yv.w), cp, v.w);
    }
    AsT[(c4 * 4 + 0) * 64 + r] = v.x;
    AsT[(c4 * 4 + 1) * 64 + r] = v.y;
    AsT[(c4 * 4 + 2) * 64 + r] = v.z;
    AsT[(c4 * 4 + 3) * 64 + r] = v.w;
  }

  float acc[4][8];
#pragma unroll
  for (int i = 0; i < 4; ++i)
#pragma unroll
    for (int j = 0; j < 8; ++j) acc[i][j] = 0.f;

  const int tx = tid & 15, ty = tid >> 4;

  for (int kh = 0; kh < 2; ++kh) {
    __syncthreads();
#pragma unroll
    for (int i = 0; i < 8; ++i) {
      int idx = i * 256 + tid;
      reinterpret_cast<float4*>(Bs)[idx] =
          reinterpret_cast<const float4*>(B)[kh * 2048 + idx];
    }
    __syncthreads();
#pragma unroll 4
    for (int k = 0; k < 64; k += 4) {
#pragma unroll
      for (int kk = 0; kk < 4; ++kk) {
        const int kg = kh * 64 + k + kk;
        const float4 av = *reinterpret_cast<const float4*>(&AsT[kg * 64 + ty * 4]);
        const float4 v0 = *reinterpret_cast<const float4*>(&Bs[(k + kk) * D + tx * 8]);
        const float4 v1 = *reinterpret_cast<const float4*>(&Bs[(k + kk) * D + tx * 8 + 4]);
        float bv[8] = {v0.x, v0.y, v0.z, v0.w, v1.x, v1.y, v1.z, v1.w};
#pragma unroll
        for (int j = 0; j < 8; ++j) {
          acc[0][j] += av.x * bv[j];
          acc[1][j] += av.y * bv[j];
          acc[2][j] += av.z * bv[j];
          acc[3][j] += av.w * bv[j];
        }
      }
    }
  }

  float sj[8], bj[8];
#pragma unroll
  for (int j = 0; j < 8; ++j) { sj[j] = shd[tx * 8 + j]; bj[j] = bd[tx * 8 + j]; }
#pragma unroll
  for (int i = 0; i < 4; ++i) {
    int gr = row0 + ty * 4 + i;
    if (gr < M) {
      float rb = rs2[gr] + ck[gr] + 1.0f;
      float4 o0 = make_float4(acc[i][0] + rb * sj[0] + bj[0],
                              acc[i][1] + rb * sj[1] + bj[1],
                              acc[i][2] + rb * sj[2] + bj[2],
                              acc[i][3] + rb * sj[3] + bj[3]);
      float4 o1 = make_float4(acc[i][4] + rb * sj[4] + bj[4],
                              acc[i][5] + rb * sj[5] + bj[5],
                              acc[i][6] + rb * sj[6] + bj[6],
                              acc[i][7] + rb * sj[7] + bj[7]);
      reinterpret_cast<float4*>(y2)[(size_t)gr * 32 + tx * 2] = o0;
      reinterpret_cast<float4*>(y2)[(size_t)gr * 32 + tx * 2 + 1] = o1;
    }
  }
}

// ---------------------------------------------------------------------------
// Final: out[r] = l2n([l2n(x_r), l2n(y1_r), l2n(y2_r)]) — y1 is bf16.
// ---------------------------------------------------------------------------
__global__ __launch_bounds__(128) void finalize_kernel(
    const float* __restrict__ x, const ushort* __restrict__ y1,
    const float* __restrict__ y2, float* __restrict__ out) {
  int r = blockIdx.x, d = threadIdx.x;
  float vx = x[(size_t)r * D + d];
  float v1 = bf2f(y1[(size_t)r * D + d]);
  float v2 = y2[(size_t)r * D + d];
  float s0 = vx * vx, s1 = v1 * v1, s2 = v2 * v2;
#pragma unroll
  for (int m = 1; m < 64; m <<= 1) {
    s0 += __shfl_xor(s0, m);
    s1 += __shfl_xor(s1, m);
    s2 += __shfl_xor(s2, m);
  }
  __shared__ float sw[2][3];
  int w = d >> 6;
  if ((d & 63) == 0) { sw[w][0] = s0; sw[w][1] = s1; sw[w][2] = s2; }
  __syncthreads();
  s0 = sw[0][0] + sw[1][0];
  s1 = sw[0][1] + sw[1][1];
  s2 = sw[0][2] + sw[1][2];
  float i0 = 1.0f / sqrtf(fmaxf(s0, L2_EPS));
  float i1 = 1.0f / sqrtf(fmaxf(s1, L2_EPS));
  float i2 = 1.0f / sqrtf(fmaxf(s2, L2_EPS));
  float tot = s0 * i0 * i0 + s1 * i1 * i1 + s2 * i2 * i2;
  float sc = 1.0f / sqrtf(fmaxf(tot, L2_EPS));
  out[(size_t)r * 384 + d] = vx * i0 * sc;
  out[(size_t)r * 384 + 128 + d] = v1 * i1 * sc;
  out[(size_t)r * 384 + 256 + d] = v2 * i2 * sc;
}

// ---------------------------------------------------------------------------
extern "C" void kernel_launch(void* const* d_in, const int* in_sizes, int n_in,
                              void* d_out, int out_size, void* d_ws, size_t ws_size,
                              hipStream_t stream) {
  const float* x      = (const float*)d_in[0];
  const int*   rows   = (const int*)d_in[1];
  const int*   cols   = (const int*)d_in[2];
  const float* adj    = (const float*)d_in[3];
  const int*   rel    = (const int*)d_in[4];
  const float* gamma1 = (const float*)d_in[5];
  const float* beta1  = (const float*)d_in[6];
  const float* mean1  = (const float*)d_in[7];
  const float* var1   = (const float*)d_in[8];
  const float* W1     = (const float*)d_in[9];
  const float* b1     = (const float*)d_in[10];
  const float* gamma2 = (const float*)d_in[11];
  const float* beta2  = (const float*)d_in[12];
  const float* mean2  = (const float*)d_in[13];
  const float* var2   = (const float*)d_in[14];
  const float* relc   = (const float*)d_in[15];
  const float* ck     = (const float*)d_in[16];
  const float* Wd     = (const float*)d_in[17];
  const float* bd     = (const float*)d_in[18];
  float* out = (float*)d_out;

  const int n = in_sizes[0] / D;
  const int e = in_sizes[1];

  float* ws = (float*)d_ws;
  size_t nd = (size_t)n * D;
  float*  agg  = ws;                      // nd (agg1, then agg2)
  float*  y2   = ws + nd;                 // nd
  ushort* xbf  = (ushort*)(ws + 2 * nd);  // nd ushorts
  ushort* y1bf = (ushort*)(ws + 2 * nd) + nd;
  float*  W1s  = ws + 3 * nd;
  float*  Wds  = W1s + D * D;
  float*  bnb  = Wds + D * D;
  float*  shd  = bnb + D;
  float*  rs1  = shd + D;
  float*  rs2  = rs1 + n;
  int* row_ptr = (int*)(rs2 + n);

  build_row_ptr_kernel<<<(n + 1 + 255) / 256, 256, 0, stream>>>(rows, row_ptr, n, e);
  scale_w_kernel<<<D, D, 0, stream>>>(W1, gamma1, var1, W1s);
  scale_w_kernel<<<D, D, 0, stream>>>(Wd, gamma2, var2, Wds);
  bn_bias_kernel<<<1, D, 0, stream>>>(W1, gamma1, beta1, mean1, var1, bnb);
  bn_bias_kernel<<<1, D, 0, stream>>>(Wd, gamma2, beta2, mean2, var2, shd);
  f32_to_bf16_kernel<<<(int)((nd / 4 + 255) / 256), 256, 0, stream>>>(x, xbf, (int)(nd / 4));

  int sblocks = (n + 3) / 4;
  int gblocks = (n + 63) / 64;

  spmm_bf16_kernel<false><<<sblocks, 256, 0, stream>>>(
      xbf, row_ptr, cols, adj, nullptr, nullptr, agg, rs1, n);
  gemm1_kernel<<<gblocks, 256, 0, stream>>>(agg, W1s, bnb, b1, rs1, y1bf, n);
  spmm_bf16_kernel<true><<<sblocks, 256, 0, stream>>>(
      y1bf, row_ptr, cols, adj, rel, relc, agg, rs2, n);
  gemm2_kernel<<<gblocks, 256, 0, stream>>>(agg, y1bf, ck, Wds, shd, bd, rs2, y2, n);
  finalize_kernel<<<n, 128, 0, stream>>>(x, y1bf, y2, out);
}

// Round 3
// 275.611 us; speedup vs baseline: 1.7205x; 1.4838x over previous
//
#include <hip/hip_runtime.h>
#include <math.h>

#define D 128
#define BN_EPS 1e-3f
#define L2_EPS 1e-12f

typedef unsigned int uint;
typedef unsigned short ushort;
typedef __attribute__((ext_vector_type(8))) short bf16x8;  // 8 bf16 in 4 VGPRs
typedef __attribute__((ext_vector_type(4))) float f32x4;

__device__ __forceinline__ ushort f2bf(float f) {
  uint u = __float_as_uint(f);
  uint r = (u + 0x7fffu + ((u >> 16) & 1u)) >> 16;
  return (ushort)r;
}
__device__ __forceinline__ float bflo(uint u) { return __uint_as_float(u << 16); }
__device__ __forceinline__ float bfhi(uint u) { return __uint_as_float(u & 0xffff0000u); }
__device__ __forceinline__ float bf2f(ushort h) { return __uint_as_float(((uint)h) << 16); }

// ---------------------------------------------------------------------------
// row_ptr[i] = lower_bound(rows, i); rows sorted ascending.
// ---------------------------------------------------------------------------
__global__ void build_row_ptr_kernel(const int* __restrict__ rows,
                                     int* __restrict__ row_ptr, int n, int e) {
  int i = blockIdx.x * blockDim.x + threadIdx.x;
  if (i > n) return;
  int lo = 0, hi = e;
  while (lo < hi) {
    int mid = (lo + hi) >> 1;
    if (rows[mid] < i) lo = mid + 1; else hi = mid;
  }
  row_ptr[i] = lo;
}

// outb[j] = sum_k (beta[k] - mean[k]*s[k]) * W[k][j]
__global__ void bn_bias_kernel(const float* __restrict__ W,
                               const float* __restrict__ gamma,
                               const float* __restrict__ beta,
                               const float* __restrict__ mean,
                               const float* __restrict__ var,
                               float* __restrict__ outb) {
  int j = threadIdx.x;
  float acc = 0.f;
  for (int k = 0; k < D; ++k) {
    float s = gamma[k] * rsqrtf(var[k] + BN_EPS);
    float sh = beta[k] - mean[k] * s;
    acc += sh * W[k * D + j];
  }
  outb[j] = acc;
}

// fp32 -> bf16 (RN), 4 elems/thread
__global__ void f32_to_bf16_kernel(const float* __restrict__ in,
                                   ushort* __restrict__ out, int n4) {
  int i = blockIdx.x * blockDim.x + threadIdx.x;
  if (i >= n4) return;
  float4 v = reinterpret_cast<const float4*>(in)[i];
  ushort4 o;
  o.x = f2bf(v.x); o.y = f2bf(v.y); o.z = f2bf(v.z); o.w = f2bf(v.w);
  reinterpret_cast<ushort4*>(out)[i] = o;
}

// ---------------------------------------------------------------------------
// Pack BN-scaled weight matrix into MFMA B-operand fragment layout (bf16):
// Bf[((kc*8+nt)*64 + lane)*8 + j] = s[k] * W[k][nt*16 + (lane&15)],
//   k = kc*32 + (lane>>4)*8 + j.   (2048 threads, one 16B fragment each)
// ---------------------------------------------------------------------------
__global__ void pack_bfrag_kernel(const float* __restrict__ W,
                                  const float* __restrict__ gamma,
                                  const float* __restrict__ var,
                                  ushort* __restrict__ Bf) {
  int t = blockIdx.x * 256 + threadIdx.x;  // 0..2047
  int f = t >> 6, lane = t & 63;
  int kc = f >> 3, nt = f & 7, q = lane >> 4, m = lane & 15;
  ushort tmp[8];
#pragma unroll
  for (int j = 0; j < 8; ++j) {
    int k = kc * 32 + q * 8 + j;
    float s = gamma[k] * rsqrtf(var[k] + BN_EPS);
    tmp[j] = f2bf(s * W[k * D + nt * 16 + m]);
  }
  uint4 o;
  o.x = (uint)tmp[0] | ((uint)tmp[1] << 16);
  o.y = (uint)tmp[2] | ((uint)tmp[3] << 16);
  o.z = (uint)tmp[4] | ((uint)tmp[5] << 16);
  o.w = (uint)tmp[6] | ((uint)tmp[7] << 16);
  reinterpret_cast<uint4*>(Bf)[t] = o;
}

// ---------------------------------------------------------------------------
// SpMM (CSR pull, wave-per-row, bf16 in/out, unroll-4 gathers):
//   outA[r] = sum_e w_e * src[cols[e]]  (+ SELF: src[r]*(ck[r]+1))
//   rowsum[r] = sum_e w_e.     REL: w_e = vals[e] / (relc[rel_ids[e]]+1).
// Lane l covers features 2l,2l+1 via one uint (256 B/edge coalesced).
// ---------------------------------------------------------------------------
template <bool REL, bool SELF>
__global__ __launch_bounds__(256) void spmm_kernel(
    const ushort* __restrict__ src, const int* __restrict__ row_ptr,
    const int* __restrict__ cols, const float* __restrict__ vals,
    const int* __restrict__ rel_ids, const float* __restrict__ relc,
    const float* __restrict__ ck, ushort* __restrict__ outA,
    float* __restrict__ rowsum, int n) {
  const int wave = threadIdx.x >> 6, lane = threadIdx.x & 63;
  const int r = blockIdx.x * 4 + wave;
  if (r >= n) return;
  const uint* S = reinterpret_cast<const uint*>(src);  // row stride 64 uints
  int e0 = row_ptr[r], e1 = row_ptr[r + 1];
  float a0 = 0.f, a1 = 0.f, b0 = 0.f, b1 = 0.f, ws = 0.f;
  int e = e0;
  for (; e + 4 <= e1; e += 4) {
    int c0 = cols[e], c1 = cols[e + 1], c2 = cols[e + 2], c3 = cols[e + 3];
    float w0 = vals[e], w1 = vals[e + 1], w2 = vals[e + 2], w3 = vals[e + 3];
    if (REL) {
      w0 /= (relc[rel_ids[e]] + 1.0f);
      w1 /= (relc[rel_ids[e + 1]] + 1.0f);
      w2 /= (relc[rel_ids[e + 2]] + 1.0f);
      w3 /= (relc[rel_ids[e + 3]] + 1.0f);
    }
    uint u0 = S[(size_t)c0 * 64 + lane];
    uint u1 = S[(size_t)c1 * 64 + lane];
    uint u2 = S[(size_t)c2 * 64 + lane];
    uint u3 = S[(size_t)c3 * 64 + lane];
    a0 = fmaf(w0, bflo(u0), a0); a1 = fmaf(w0, bfhi(u0), a1);
    b0 = fmaf(w1, bflo(u1), b0); b1 = fmaf(w1, bfhi(u1), b1);
    a0 = fmaf(w2, bflo(u2), a0); a1 = fmaf(w2, bfhi(u2), a1);
    b0 = fmaf(w3, bflo(u3), b0); b1 = fmaf(w3, bfhi(u3), b1);
    ws += (w0 + w1) + (w2 + w3);
  }
  for (; e < e1; ++e) {
    int c = cols[e];
    float w = vals[e];
    if (REL) w /= (relc[rel_ids[e]] + 1.0f);
    uint u = S[(size_t)c * 64 + lane];
    a0 = fmaf(w, bflo(u), a0); a1 = fmaf(w, bfhi(u), a1);
    ws += w;
  }
  if (SELF) {
    uint us = S[(size_t)r * 64 + lane];
    float cp = ck[r] + 1.0f;
    a0 = fmaf(cp, bflo(us), a0); a1 = fmaf(cp, bfhi(us), a1);
  }
  a0 += b0; a1 += b1;
  reinterpret_cast<uint*>(outA)[(size_t)r * 64 + lane] =
      (uint)f2bf(a0) | ((uint)f2bf(a1) << 16);
  if (lane == 0) rowsum[r] = ws;
}

// ---------------------------------------------------------------------------
// GEMM1 (MFMA, no LDS, no barriers): y1 = tanh(A @ Ws + rs1*bnb + b1), bf16.
// Wave = 16 rows. Operand-swapped mfma => lane holds row (lane&15) and
// 4 consecutive cols ((lane>>4)*4 + reg) per 16-col tile.
// ---------------------------------------------------------------------------
__global__ __launch_bounds__(256) void gemm1_mfma_kernel(
    const ushort* __restrict__ A, const ushort* __restrict__ Bf,
    const float* __restrict__ bnb, const float* __restrict__ b1,
    const float* __restrict__ rs1, ushort* __restrict__ y1, int M) {
  const int wave = threadIdx.x >> 6, lane = threadIdx.x & 63;
  const int row0 = blockIdx.x * 64 + wave * 16;
  if (row0 >= M) return;
  const int m = lane & 15, q = lane >> 4;
  const int row = row0 + m;
  const int arow = row < M ? row : M - 1;

  const bf16x8* Av = reinterpret_cast<const bf16x8*>(A);  // row stride: 16 frags
  const bf16x8* Bv = reinterpret_cast<const bf16x8*>(Bf);

  bf16x8 af[4];
#pragma unroll
  for (int kc = 0; kc < 4; ++kc) af[kc] = Av[(size_t)arow * 16 + kc * 4 + q];

  f32x4 acc[8];
#pragma unroll
  for (int nt = 0; nt < 8; ++nt) acc[nt] = (f32x4){0.f, 0.f, 0.f, 0.f};

#pragma unroll
  for (int kc = 0; kc < 4; ++kc) {
#pragma unroll
    for (int nt = 0; nt < 8; ++nt) {
      bf16x8 b = Bv[(kc * 8 + nt) * 64 + lane];
      acc[nt] = __builtin_amdgcn_mfma_f32_16x16x32_bf16(b, af[kc], acc[nt], 0, 0, 0);
    }
  }

  if (row < M) {
    float rs = rs1[row];
#pragma unroll
    for (int nt = 0; nt < 8; ++nt) {
      const float4 bn = *reinterpret_cast<const float4*>(&bnb[nt * 16 + q * 4]);
      const float4 bb = *reinterpret_cast<const float4*>(&b1[nt * 16 + q * 4]);
      ushort4 o;
      o.x = f2bf(tanhf(acc[nt][0] + rs * bn.x + bb.x));
      o.y = f2bf(tanhf(acc[nt][1] + rs * bn.y + bb.y));
      o.z = f2bf(tanhf(acc[nt][2] + rs * bn.z + bb.z));
      o.w = f2bf(tanhf(acc[nt][3] + rs * bn.w + bb.w));
      *reinterpret_cast<ushort4*>(&y1[(size_t)row * D + nt * 16 + q * 4]) = o;
    }
  }
}

// ---------------------------------------------------------------------------
// GEMM2 + finalize (fused): y2 = A2 @ Wds + (rs2+ck+1)*shd + bd, then
// out[r] = l2n([l2n(x_r), l2n(y1_r), l2n(y2_r)]).  A wave holds 16 full rows;
// per-row norms via shfl_xor(16|32) across the 4 lanes sharing a row.
// ---------------------------------------------------------------------------
__global__ __launch_bounds__(256) void gemm2_fused_kernel(
    const ushort* __restrict__ A2, const ushort* __restrict__ Bf,
    const float* __restrict__ shd, const float* __restrict__ bd,
    const float* __restrict__ rs2, const float* __restrict__ ck,
    const float* __restrict__ x, const ushort* __restrict__ y1,
    float* __restrict__ out, int M) {
  const int wave = threadIdx.x >> 6, lane = threadIdx.x & 63;
  const int row0 = blockIdx.x * 64 + wave * 16;
  if (row0 >= M) return;
  const int m = lane & 15, q = lane >> 4;
  const int row = row0 + m;
  const int arow = row < M ? row : M - 1;

  const bf16x8* Av = reinterpret_cast<const bf16x8*>(A2);
  const bf16x8* Bv = reinterpret_cast<const bf16x8*>(Bf);

  bf16x8 af[4];
#pragma unroll
  for (int kc = 0; kc < 4; ++kc) af[kc] = Av[(size_t)arow * 16 + kc * 4 + q];

  f32x4 acc[8];
#pragma unroll
  for (int nt = 0; nt < 8; ++nt) acc[nt] = (f32x4){0.f, 0.f, 0.f, 0.f};

#pragma unroll
  for (int kc = 0; kc < 4; ++kc) {
#pragma unroll
    for (int nt = 0; nt < 8; ++nt) {
      bf16x8 b = Bv[(kc * 8 + nt) * 64 + lane];
      acc[nt] = __builtin_amdgcn_mfma_f32_16x16x32_bf16(b, af[kc], acc[nt], 0, 0, 0);
    }
  }

  // epilogue: y2 values in acc (overwritten), gather x & y1, 3 row-norms
  const float rb = rs2[arow] + ck[arow] + 1.0f;
  float4 xv[8];
  ushort4 y1v[8];
  float s0 = 0.f, s1 = 0.f, s2 = 0.f;
#pragma unroll
  for (int nt = 0; nt < 8; ++nt) {
    const float4 sh = *reinterpret_cast<const float4*>(&shd[nt * 16 + q * 4]);
    const float4 bb = *reinterpret_cast<const float4*>(&bd[nt * 16 + q * 4]);
    acc[nt][0] += rb * sh.x + bb.x;
    acc[nt][1] += rb * sh.y + bb.y;
    acc[nt][2] += rb * sh.z + bb.z;
    acc[nt][3] += rb * sh.w + bb.w;
    s2 += acc[nt][0] * acc[nt][0] + acc[nt][1] * acc[nt][1] +
          acc[nt][2] * acc[nt][2] + acc[nt][3] * acc[nt][3];
    xv[nt] = *reinterpret_cast<const float4*>(&x[(size_t)arow * D + nt * 16 + q * 4]);
    s0 += xv[nt].x * xv[nt].x + xv[nt].y * xv[nt].y +
          xv[nt].z * xv[nt].z + xv[nt].w * xv[nt].w;
    y1v[nt] = *reinterpret_cast<const ushort4*>(&y1[(size_t)arow * D + nt * 16 + q * 4]);
    float ya = bf2f(y1v[nt].x), yb = bf2f(y1v[nt].y);
    float yc = bf2f(y1v[nt].z), yd = bf2f(y1v[nt].w);
    s1 += ya * ya + yb * yb + yc * yc + yd * yd;
  }
  s0 += __shfl_xor(s0, 16); s0 += __shfl_xor(s0, 32);
  s1 += __shfl_xor(s1, 16); s1 += __shfl_xor(s1, 32);
  s2 += __shfl_xor(s2, 16); s2 += __shfl_xor(s2, 32);
  const float i0 = 1.0f / sqrtf(fmaxf(s0, L2_EPS));
  const float i1 = 1.0f / sqrtf(fmaxf(s1, L2_EPS));
  const float i2 = 1.0f / sqrtf(fmaxf(s2, L2_EPS));
  const float tot = s0 * i0 * i0 + s1 * i1 * i1 + s2 * i2 * i2;
  const float sc = 1.0f / sqrtf(fmaxf(tot, L2_EPS));
  const float f0 = i0 * sc, f1 = i1 * sc, f2 = i2 * sc;

  if (row < M) {
    float* orow = out + (size_t)row * 384;
#pragma unroll
    for (int nt = 0; nt < 8; ++nt) {
      const int c = nt * 16 + q * 4;
      float4 ox = make_float4(xv[nt].x * f0, xv[nt].y * f0, xv[nt].z * f0, xv[nt].w * f0);
      float4 oy = make_float4(bf2f(y1v[nt].x) * f1, bf2f(y1v[nt].y) * f1,
                              bf2f(y1v[nt].z) * f1, bf2f(y1v[nt].w) * f1);
      float4 oz = make_float4(acc[nt][0] * f2, acc[nt][1] * f2,
                              acc[nt][2] * f2, acc[nt][3] * f2);
      *reinterpret_cast<float4*>(orow + c) = ox;
      *reinterpret_cast<float4*>(orow + 128 + c) = oy;
      *reinterpret_cast<float4*>(orow + 256 + c) = oz;
    }
  }
}

// ---------------------------------------------------------------------------
extern "C" void kernel_launch(void* const* d_in, const int* in_sizes, int n_in,
                              void* d_out, int out_size, void* d_ws, size_t ws_size,
                              hipStream_t stream) {
  const float* x      = (const float*)d_in[0];
  const int*   rows   = (const int*)d_in[1];
  const int*   cols   = (const int*)d_in[2];
  const float* adj    = (const float*)d_in[3];
  const int*   rel    = (const int*)d_in[4];
  const float* gamma1 = (const float*)d_in[5];
  const float* beta1  = (const float*)d_in[6];
  const float* mean1  = (const float*)d_in[7];
  const float* var1   = (const float*)d_in[8];
  const float* W1     = (const float*)d_in[9];
  const float* b1     = (const float*)d_in[10];
  const float* gamma2 = (const float*)d_in[11];
  const float* beta2  = (const float*)d_in[12];
  const float* mean2  = (const float*)d_in[13];
  const float* var2   = (const float*)d_in[14];
  const float* relc   = (const float*)d_in[15];
  const float* ck     = (const float*)d_in[16];
  const float* Wd     = (const float*)d_in[17];
  const float* bd     = (const float*)d_in[18];
  float* out = (float*)d_out;

  const int n = in_sizes[0] / D;
  const int e = in_sizes[1];
  size_t nd = (size_t)n * D;

  ushort* xbf   = (ushort*)d_ws;        // nd bf16
  ushort* y1bf  = xbf + nd;             // nd bf16
  ushort* aggbf = y1bf + nd;            // nd bf16 (agg1, then A2)
  ushort* Bf1   = aggbf + nd;           // 16384 bf16 (fragment-packed W1s)
  ushort* Bf2   = Bf1 + 16384;          // 16384 bf16 (fragment-packed Wds)
  float*  bnb   = (float*)(Bf2 + 16384);
  float*  shd   = bnb + D;
  float*  rs1   = shd + D;
  float*  rs2   = rs1 + n;
  int* row_ptr  = (int*)(rs2 + n);

  build_row_ptr_kernel<<<(n + 1 + 255) / 256, 256, 0, stream>>>(rows, row_ptr, n, e);
  pack_bfrag_kernel<<<8, 256, 0, stream>>>(W1, gamma1, var1, Bf1);
  pack_bfrag_kernel<<<8, 256, 0, stream>>>(Wd, gamma2, var2, Bf2);
  bn_bias_kernel<<<1, D, 0, stream>>>(W1, gamma1, beta1, mean1, var1, bnb);
  bn_bias_kernel<<<1, D, 0, stream>>>(Wd, gamma2, beta2, mean2, var2, shd);
  f32_to_bf16_kernel<<<(int)((nd / 4 + 255) / 256), 256, 0, stream>>>(x, xbf, (int)(nd / 4));

  int sblocks = (n + 3) / 4;
  int gblocks = (n + 63) / 64;

  spmm_kernel<false, false><<<sblocks, 256, 0, stream>>>(
      xbf, row_ptr, cols, adj, nullptr, nullptr, nullptr, aggbf, rs1, n);
  gemm1_mfma_kernel<<<gblocks, 256, 0, stream>>>(aggbf, Bf1, bnb, b1, rs1, y1bf, n);
  spmm_kernel<true, true><<<sblocks, 256, 0, stream>>>(
      y1bf, row_ptr, cols, adj, rel, relc, ck, aggbf, rs2, n);
  gemm2_fused_kernel<<<gblocks, 256, 0, stream>>>(
      aggbf, Bf2, shd, bd, rs2, ck, x, y1bf, out, n);
}

// Round 4
// 258.285 us; speedup vs baseline: 1.8359x; 1.0671x over previous
//
#include <hip/hip_runtime.h>
#include <math.h>

#define D 128
#define BN_EPS 1e-3f
#define L2_EPS 1e-12f

typedef unsigned int uint;
typedef unsigned short ushort;
typedef __attribute__((ext_vector_type(8))) short bf16x8;  // 8 bf16 in 4 VGPRs
typedef __attribute__((ext_vector_type(4))) float f32x4;

__device__ __forceinline__ ushort f2bf(float f) {
  uint u = __float_as_uint(f);
  uint r = (u + 0x7fffu + ((u >> 16) & 1u)) >> 16;
  return (ushort)r;
}
__device__ __forceinline__ float bflo(uint u) { return __uint_as_float(u << 16); }
__device__ __forceinline__ float bfhi(uint u) { return __uint_as_float(u & 0xffff0000u); }
__device__ __forceinline__ float bf2f(ushort h) { return __uint_as_float(((uint)h) << 16); }

// ---------------------------------------------------------------------------
// Device helpers for the fused prep kernel
// ---------------------------------------------------------------------------
__device__ __forceinline__ void pack_bfrag_block(
    const float* __restrict__ W, const float* __restrict__ gamma,
    const float* __restrict__ var, ushort* __restrict__ Bf, int blk, int tid) {
  int t = blk * 256 + tid;  // 0..2047
  int f = t >> 6, lane = t & 63;
  int kc = f >> 3, nt = f & 7, q = lane >> 4, m = lane & 15;
  ushort tmp[8];
#pragma unroll
  for (int j = 0; j < 8; ++j) {
    int k = kc * 32 + q * 8 + j;
    float s = gamma[k] * rsqrtf(var[k] + BN_EPS);
    tmp[j] = f2bf(s * W[k * D + nt * 16 + m]);
  }
  uint4 o;
  o.x = (uint)tmp[0] | ((uint)tmp[1] << 16);
  o.y = (uint)tmp[2] | ((uint)tmp[3] << 16);
  o.z = (uint)tmp[4] | ((uint)tmp[5] << 16);
  o.w = (uint)tmp[6] | ((uint)tmp[7] << 16);
  reinterpret_cast<uint4*>(Bf)[t] = o;
}

__device__ __forceinline__ void bn_bias_block(
    const float* __restrict__ W, const float* __restrict__ gamma,
    const float* __restrict__ beta, const float* __restrict__ mean,
    const float* __restrict__ var, float* __restrict__ outb, int j) {
  float acc = 0.f;
  for (int k = 0; k < D; ++k) {
    float s = gamma[k] * rsqrtf(var[k] + BN_EPS);
    float sh = beta[k] - mean[k] * s;
    acc += sh * W[k * D + j];
  }
  outb[j] = acc;
}

// ---------------------------------------------------------------------------
// Fused prep: [0,nbConv) f32->bf16 | [nbConv,+nbRp) row_ptr lower-bound |
// +8 pack Bf1 | +8 pack Bf2 | +1 bnb | +1 shd | rest: recip table.
// ---------------------------------------------------------------------------
__global__ __launch_bounds__(256) void prep_kernel(
    const float* __restrict__ x, ushort* __restrict__ xbf, int n4,
    const int* __restrict__ rows, int* __restrict__ row_ptr, int n, int e,
    const float* __restrict__ W1, const float* __restrict__ g1,
    const float* __restrict__ v1, ushort* __restrict__ Bf1,
    const float* __restrict__ Wd, const float* __restrict__ g2,
    const float* __restrict__ v2, ushort* __restrict__ Bf2,
    const float* __restrict__ beta1, const float* __restrict__ mean1,
    float* __restrict__ bnb,
    const float* __restrict__ beta2, const float* __restrict__ mean2,
    float* __restrict__ shd,
    const float* __restrict__ relc, float* __restrict__ recip, int nrel,
    int nbConv, int nbRp) {
  const int b = blockIdx.x, tid = threadIdx.x;
  if (b < nbConv) {
    int i = b * 256 + tid;
    if (i < n4) {
      float4 v = reinterpret_cast<const float4*>(x)[i];
      ushort4 o;
      o.x = f2bf(v.x); o.y = f2bf(v.y); o.z = f2bf(v.z); o.w = f2bf(v.w);
      reinterpret_cast<ushort4*>(xbf)[i] = o;
    }
    return;
  }
  int bb = b - nbConv;
  if (bb < nbRp) {
    int i = bb * 256 + tid;
    if (i <= n) {
      int lo = 0, hi = e;
      while (lo < hi) {
        int mid = (lo + hi) >> 1;
        if (rows[mid] < i) lo = mid + 1; else hi = mid;
      }
      row_ptr[i] = lo;
    }
    return;
  }
  bb -= nbRp;
  if (bb < 8) { pack_bfrag_block(W1, g1, v1, Bf1, bb, tid); return; }
  if (bb < 16) { pack_bfrag_block(Wd, g2, v2, Bf2, bb - 8, tid); return; }
  if (bb == 16) { if (tid < D) bn_bias_block(W1, g1, beta1, mean1, v1, bnb, tid); return; }
  if (bb == 17) { if (tid < D) bn_bias_block(Wd, g2, beta2, mean2, v2, shd, tid); return; }
  int i = (bb - 18) * 256 + tid;
  if (i < nrel) recip[i] = 1.0f / (relc[i] + 1.0f);
}

// ---------------------------------------------------------------------------
// SpMM (CSR pull, wave-per-row, bf16 in/out, masked unroll-8):
//   outA[r] = sum_e w_e * src[cols[e]]  (+ SELF: src[r]*(ck[r]+1))
//   rowsum[r] = sum_e w_e.   REL: w_e = vals[e] * recip[rel_ids[e]].
// Lane l covers features 2l,2l+1 via one uint (256 B/edge coalesced).
// Masked slots clamp to the last edge (L1-hot re-read) with weight 0 -> no
// serial tail, 8 gathers in flight per wave.
// ---------------------------------------------------------------------------
template <bool REL, bool SELF>
__global__ __launch_bounds__(256) void spmm_kernel(
    const ushort* __restrict__ src, const int* __restrict__ row_ptr,
    const int* __restrict__ cols, const float* __restrict__ vals,
    const int* __restrict__ rel_ids, const float* __restrict__ recip,
    const float* __restrict__ ck, ushort* __restrict__ outA,
    float* __restrict__ rowsum, int n) {
  const int wave = threadIdx.x >> 6, lane = threadIdx.x & 63;
  const int r = blockIdx.x * 4 + wave;
  if (r >= n) return;
  const uint* S = reinterpret_cast<const uint*>(src);  // row stride 64 uints
  const int e0 = row_ptr[r], e1 = row_ptr[r + 1];
  const int last = e1 - 1;
  float a0 = 0.f, a1 = 0.f, b0 = 0.f, b1 = 0.f, ws = 0.f;
  for (int base = e0; base < e1; base += 8) {
    int c[8]; float w[8];
#pragma unroll
    for (int u = 0; u < 8; ++u) {
      int ee = base + u;
      int eC = ee < last ? ee : last;  // clamp (uniform select)
      c[u] = cols[eC];
      float wv = vals[eC];
      if (REL) wv *= recip[rel_ids[eC]];
      w[u] = (ee <= last) ? wv : 0.f;
    }
    uint g[8];
#pragma unroll
    for (int u = 0; u < 8; ++u) g[u] = S[(size_t)c[u] * 64 + lane];
#pragma unroll
    for (int u = 0; u < 8; u += 2) {
      a0 = fmaf(w[u], bflo(g[u]), a0);
      a1 = fmaf(w[u], bfhi(g[u]), a1);
      b0 = fmaf(w[u + 1], bflo(g[u + 1]), b0);
      b1 = fmaf(w[u + 1], bfhi(g[u + 1]), b1);
      ws += w[u] + w[u + 1];
    }
  }
  if (SELF) {
    uint us = S[(size_t)r * 64 + lane];
    float cp = ck[r] + 1.0f;
    a0 = fmaf(cp, bflo(us), a0);
    a1 = fmaf(cp, bfhi(us), a1);
  }
  a0 += b0; a1 += b1;
  reinterpret_cast<uint*>(outA)[(size_t)r * 64 + lane] =
      (uint)f2bf(a0) | ((uint)f2bf(a1) << 16);
  if (lane == 0) rowsum[r] = ws;
}

// ---------------------------------------------------------------------------
// GEMM1 (MFMA, no LDS, no barriers): y1 = tanh(A @ Ws + rs1*bnb + b1), bf16.
// Wave = 16 rows. Operand-swapped mfma => lane holds row (lane&15) and
// 4 consecutive cols ((lane>>4)*4 + reg) per 16-col tile.
// ---------------------------------------------------------------------------
__global__ __launch_bounds__(256) void gemm1_mfma_kernel(
    const ushort* __restrict__ A, const ushort* __restrict__ Bf,
    const float* __restrict__ bnb, const float* __restrict__ b1,
    const float* __restrict__ rs1, ushort* __restrict__ y1, int M) {
  const int wave = threadIdx.x >> 6, lane = threadIdx.x & 63;
  const int row0 = blockIdx.x * 64 + wave * 16;
  if (row0 >= M) return;
  const int m = lane & 15, q = lane >> 4;
  const int row = row0 + m;
  const int arow = row < M ? row : M - 1;

  const bf16x8* Av = reinterpret_cast<const bf16x8*>(A);  // row stride: 16 frags
  const bf16x8* Bv = reinterpret_cast<const bf16x8*>(Bf);

  bf16x8 af[4];
#pragma unroll
  for (int kc = 0; kc < 4; ++kc) af[kc] = Av[(size_t)arow * 16 + kc * 4 + q];

  f32x4 acc[8];
#pragma unroll
  for (int nt = 0; nt < 8; ++nt) acc[nt] = (f32x4){0.f, 0.f, 0.f, 0.f};

#pragma unroll
  for (int kc = 0; kc < 4; ++kc) {
#pragma unroll
    for (int nt = 0; nt < 8; ++nt) {
      bf16x8 b = Bv[(kc * 8 + nt) * 64 + lane];
      acc[nt] = __builtin_amdgcn_mfma_f32_16x16x32_bf16(b, af[kc], acc[nt], 0, 0, 0);
    }
  }

  if (row < M) {
    float rs = rs1[row];
#pragma unroll
    for (int nt = 0; nt < 8; ++nt) {
      const float4 bn = *reinterpret_cast<const float4*>(&bnb[nt * 16 + q * 4]);
      const float4 bb = *reinterpret_cast<const float4*>(&b1[nt * 16 + q * 4]);
      ushort4 o;
      o.x = f2bf(tanhf(acc[nt][0] + rs * bn.x + bb.x));
      o.y = f2bf(tanhf(acc[nt][1] + rs * bn.y + bb.y));
      o.z = f2bf(tanhf(acc[nt][2] + rs * bn.z + bb.z));
      o.w = f2bf(tanhf(acc[nt][3] + rs * bn.w + bb.w));
      *reinterpret_cast<ushort4*>(&y1[(size_t)row * D + nt * 16 + q * 4]) = o;
    }
  }
}

// ---------------------------------------------------------------------------
// GEMM2 + finalize (fused): y2 = A2 @ Wds + (rs2+ck+1)*shd + bd, then
// out[r] = l2n([l2n(x_r), l2n(y1_r), l2n(y2_r)]).  A wave holds 16 full rows;
// per-row norms via shfl_xor(16|32) across the 4 lanes sharing a row.
// ---------------------------------------------------------------------------
__global__ __launch_bounds__(256) void gemm2_fused_kernel(
    const ushort* __restrict__ A2, const ushort* __restrict__ Bf,
    const float* __restrict__ shd, const float* __restrict__ bd,
    const float* __restrict__ rs2, const float* __restrict__ ck,
    const float* __restrict__ x, const ushort* __restrict__ y1,
    float* __restrict__ out, int M) {
  const int wave = threadIdx.x >> 6, lane = threadIdx.x & 63;
  const int row0 = blockIdx.x * 64 + wave * 16;
  if (row0 >= M) return;
  const int m = lane & 15, q = lane >> 4;
  const int row = row0 + m;
  const int arow = row < M ? row : M - 1;

  const bf16x8* Av = reinterpret_cast<const bf16x8*>(A2);
  const bf16x8* Bv = reinterpret_cast<const bf16x8*>(Bf);

  bf16x8 af[4];
#pragma unroll
  for (int kc = 0; kc < 4; ++kc) af[kc] = Av[(size_t)arow * 16 + kc * 4 + q];

  f32x4 acc[8];
#pragma unroll
  for (int nt = 0; nt < 8; ++nt) acc[nt] = (f32x4){0.f, 0.f, 0.f, 0.f};

#pragma unroll
  for (int kc = 0; kc < 4; ++kc) {
#pragma unroll
    for (int nt = 0; nt < 8; ++nt) {
      bf16x8 b = Bv[(kc * 8 + nt) * 64 + lane];
      acc[nt] = __builtin_amdgcn_mfma_f32_16x16x32_bf16(b, af[kc], acc[nt], 0, 0, 0);
    }
  }

  // epilogue: y2 values in acc (overwritten), gather x & y1, 3 row-norms
  const float rb = rs2[arow] + ck[arow] + 1.0f;
  float4 xv[8];
  ushort4 y1v[8];
  float s0 = 0.f, s1 = 0.f, s2 = 0.f;
#pragma unroll
  for (int nt = 0; nt < 8; ++nt) {
    const float4 sh = *reinterpret_cast<const float4*>(&shd[nt * 16 + q * 4]);
    const float4 bb = *reinterpret_cast<const float4*>(&bd[nt * 16 + q * 4]);
    acc[nt][0] += rb * sh.x + bb.x;
    acc[nt][1] += rb * sh.y + bb.y;
    acc[nt][2] += rb * sh.z + bb.z;
    acc[nt][3] += rb * sh.w + bb.w;
    s2 += acc[nt][0] * acc[nt][0] + acc[nt][1] * acc[nt][1] +
          acc[nt][2] * acc[nt][2] + acc[nt][3] * acc[nt][3];
    xv[nt] = *reinterpret_cast<const float4*>(&x[(size_t)arow * D + nt * 16 + q * 4]);
    s0 += xv[nt].x * xv[nt].x + xv[nt].y * xv[nt].y +
          xv[nt].z * xv[nt].z + xv[nt].w * xv[nt].w;
    y1v[nt] = *reinterpret_cast<const ushort4*>(&y1[(size_t)arow * D + nt * 16 + q * 4]);
    float ya = bf2f(y1v[nt].x), yb = bf2f(y1v[nt].y);
    float yc = bf2f(y1v[nt].z), yd = bf2f(y1v[nt].w);
    s1 += ya * ya + yb * yb + yc * yc + yd * yd;
  }
  s0 += __shfl_xor(s0, 16); s0 += __shfl_xor(s0, 32);
  s1 += __shfl_xor(s1, 16); s1 += __shfl_xor(s1, 32);
  s2 += __shfl_xor(s2, 16); s2 += __shfl_xor(s2, 32);
  const float i0 = 1.0f / sqrtf(fmaxf(s0, L2_EPS));
  const float i1 = 1.0f / sqrtf(fmaxf(s1, L2_EPS));
  const float i2 = 1.0f / sqrtf(fmaxf(s2, L2_EPS));
  const float tot = s0 * i0 * i0 + s1 * i1 * i1 + s2 * i2 * i2;
  const float sc = 1.0f / sqrtf(fmaxf(tot, L2_EPS));
  const float f0 = i0 * sc, f1 = i1 * sc, f2 = i2 * sc;

  if (row < M) {
    float* orow = out + (size_t)row * 384;
#pragma unroll
    for (int nt = 0; nt < 8; ++nt) {
      const int c = nt * 16 + q * 4;
      float4 ox = make_float4(xv[nt].x * f0, xv[nt].y * f0, xv[nt].z * f0, xv[nt].w * f0);
      float4 oy = make_float4(bf2f(y1v[nt].x) * f1, bf2f(y1v[nt].y) * f1,
                              bf2f(y1v[nt].z) * f1, bf2f(y1v[nt].w) * f1);
      float4 oz = make_float4(acc[nt][0] * f2, acc[nt][1] * f2,
                              acc[nt][2] * f2, acc[nt][3] * f2);
      *reinterpret_cast<float4*>(orow + c) = ox;
      *reinterpret_cast<float4*>(orow + 128 + c) = oy;
      *reinterpret_cast<float4*>(orow + 256 + c) = oz;
    }
  }
}

// ---------------------------------------------------------------------------
extern "C" void kernel_launch(void* const* d_in, const int* in_sizes, int n_in,
                              void* d_out, int out_size, void* d_ws, size_t ws_size,
                              hipStream_t stream) {
  const float* x      = (const float*)d_in[0];
  const int*   rows   = (const int*)d_in[1];
  const int*   cols   = (const int*)d_in[2];
  const float* adj    = (const float*)d_in[3];
  const int*   rel    = (const int*)d_in[4];
  const float* gamma1 = (const float*)d_in[5];
  const float* beta1  = (const float*)d_in[6];
  const float* mean1  = (const float*)d_in[7];
  const float* var1   = (const float*)d_in[8];
  const float* W1     = (const float*)d_in[9];
  const float* b1     = (const float*)d_in[10];
  const float* gamma2 = (const float*)d_in[11];
  const float* beta2  = (const float*)d_in[12];
  const float* mean2  = (const float*)d_in[13];
  const float* var2   = (const float*)d_in[14];
  const float* relc   = (const float*)d_in[15];
  const float* ck     = (const float*)d_in[16];
  const float* Wd     = (const float*)d_in[17];
  const float* bd     = (const float*)d_in[18];
  float* out = (float*)d_out;

  const int n = in_sizes[0] / D;
  const int e = in_sizes[1];
  const int nrel = in_sizes[15];
  size_t nd = (size_t)n * D;

  ushort* xbf   = (ushort*)d_ws;        // nd bf16
  ushort* y1bf  = xbf + nd;             // nd bf16
  ushort* aggbf = y1bf + nd;            // nd bf16 (agg1, then A2)
  ushort* Bf1   = aggbf + nd;           // 16384 bf16 (fragment-packed W1s)
  ushort* Bf2   = Bf1 + 16384;          // 16384 bf16 (fragment-packed Wds)
  float*  bnb   = (float*)(Bf2 + 16384);
  float*  shd   = bnb + D;
  float*  rs1   = shd + D;
  float*  rs2   = rs1 + n;
  float*  recip = rs2 + n;
  int* row_ptr  = (int*)(recip + nrel);

  const int n4 = (int)(nd / 4);
  const int nbConv = (n4 + 255) / 256;
  const int nbRp = (n + 1 + 255) / 256;
  const int nbRecip = (nrel + 255) / 256;
  const int nbPrep = nbConv + nbRp + 18 + nbRecip;

  prep_kernel<<<nbPrep, 256, 0, stream>>>(
      x, xbf, n4, rows, row_ptr, n, e,
      W1, gamma1, var1, Bf1, Wd, gamma2, var2, Bf2,
      beta1, mean1, bnb, beta2, mean2, shd,
      relc, recip, nrel, nbConv, nbRp);

  int sblocks = (n + 3) / 4;
  int gblocks = (n + 63) / 64;

  spmm_kernel<false, false><<<sblocks, 256, 0, stream>>>(
      xbf, row_ptr, cols, adj, nullptr, nullptr, nullptr, aggbf, rs1, n);
  gemm1_mfma_kernel<<<gblocks, 256, 0, stream>>>(aggbf, Bf1, bnb, b1, rs1, y1bf, n);
  spmm_kernel<true, true><<<sblocks, 256, 0, stream>>>(
      y1bf, row_ptr, cols, adj, rel, recip, ck, aggbf, rs2, n);
  gemm2_fused_kernel<<<gblocks, 256, 0, stream>>>(
      aggbf, Bf2, shd, bd, rs2, ck, x, y1bf, out, n);
}

// Round 5
// 229.319 us; speedup vs baseline: 2.0678x; 1.1263x over previous
//
#include <hip/hip_runtime.h>
#include <math.h>

#define D 128
#define BN_EPS 1e-3f
#define L2_EPS 1e-12f

typedef unsigned int uint;
typedef unsigned short ushort;
typedef __attribute__((ext_vector_type(8))) short bf16x8;  // 8 bf16 in 4 VGPRs
typedef __attribute__((ext_vector_type(4))) float f32x4;

__device__ __forceinline__ ushort f2bf(float f) {
  uint u = __float_as_uint(f);
  uint r = (u + 0x7fffu + ((u >> 16) & 1u)) >> 16;
  return (ushort)r;
}
__device__ __forceinline__ float bflo(uint u) { return __uint_as_float(u << 16); }
__device__ __forceinline__ float bfhi(uint u) { return __uint_as_float(u & 0xffff0000u); }
__device__ __forceinline__ float bf2f(ushort h) { return __uint_as_float(((uint)h) << 16); }

// ---------------------------------------------------------------------------
// Device helpers for the fused prep kernel
// ---------------------------------------------------------------------------
__device__ __forceinline__ void pack_bfrag_block(
    const float* __restrict__ W, const float* __restrict__ gamma,
    const float* __restrict__ var, ushort* __restrict__ Bf, int blk, int tid) {
  int t = blk * 256 + tid;  // 0..2047
  int f = t >> 6, lane = t & 63;
  int kc = f >> 3, nt = f & 7, q = lane >> 4, m = lane & 15;
  ushort tmp[8];
#pragma unroll
  for (int j = 0; j < 8; ++j) {
    int k = kc * 32 + q * 8 + j;
    float s = gamma[k] * rsqrtf(var[k] + BN_EPS);
    tmp[j] = f2bf(s * W[k * D + nt * 16 + m]);
  }
  uint4 o;
  o.x = (uint)tmp[0] | ((uint)tmp[1] << 16);
  o.y = (uint)tmp[2] | ((uint)tmp[3] << 16);
  o.z = (uint)tmp[4] | ((uint)tmp[5] << 16);
  o.w = (uint)tmp[6] | ((uint)tmp[7] << 16);
  reinterpret_cast<uint4*>(Bf)[t] = o;
}

__device__ __forceinline__ void bn_bias_block(
    const float* __restrict__ W, const float* __restrict__ gamma,
    const float* __restrict__ beta, const float* __restrict__ mean,
    const float* __restrict__ var, float* __restrict__ outb, int j) {
  float acc = 0.f;
  for (int k = 0; k < D; ++k) {
    float s = gamma[k] * rsqrtf(var[k] + BN_EPS);
    float sh = beta[k] - mean[k] * s;
    acc += sh * W[k * D + j];
  }
  outb[j] = acc;
}

// ---------------------------------------------------------------------------
// Fused prep: [0,nbConv) f32->bf16 | [+nbRp) row_ptr | +8 Bf1 | +8 Bf2 |
// +1 bnb | +1 shd | rest: packed edge arrays ew1=(col,adj),
// ew2=(col, adj/(relc[rel]+1)), one pad entry (0,0) at index e.
// ---------------------------------------------------------------------------
__global__ __launch_bounds__(256) void prep_kernel(
    const float* __restrict__ x, ushort* __restrict__ xbf, int n4,
    const int* __restrict__ rows, int* __restrict__ row_ptr, int n, int e,
    const float* __restrict__ W1, const float* __restrict__ g1,
    const float* __restrict__ v1, ushort* __restrict__ Bf1,
    const float* __restrict__ Wd, const float* __restrict__ g2,
    const float* __restrict__ v2, ushort* __restrict__ Bf2,
    const float* __restrict__ beta1, const float* __restrict__ mean1,
    float* __restrict__ bnb,
    const float* __restrict__ beta2, const float* __restrict__ mean2,
    float* __restrict__ shd,
    const int* __restrict__ cols, const float* __restrict__ adj,
    const int* __restrict__ rel, const float* __restrict__ relc,
    uint2* __restrict__ ew1, uint2* __restrict__ ew2,
    int nbConv, int nbRp) {
  const int b = blockIdx.x, tid = threadIdx.x;
  if (b < nbConv) {
    int i = b * 256 + tid;
    if (i < n4) {
      float4 v = reinterpret_cast<const float4*>(x)[i];
      ushort4 o;
      o.x = f2bf(v.x); o.y = f2bf(v.y); o.z = f2bf(v.z); o.w = f2bf(v.w);
      reinterpret_cast<ushort4*>(xbf)[i] = o;
    }
    return;
  }
  int bb = b - nbConv;
  if (bb < nbRp) {
    int i = bb * 256 + tid;
    if (i <= n) {
      int lo = 0, hi = e;
      while (lo < hi) {
        int mid = (lo + hi) >> 1;
        if (rows[mid] < i) lo = mid + 1; else hi = mid;
      }
      row_ptr[i] = lo;
    }
    return;
  }
  bb -= nbRp;
  if (bb < 8) { pack_bfrag_block(W1, g1, v1, Bf1, bb, tid); return; }
  if (bb < 16) { pack_bfrag_block(Wd, g2, v2, Bf2, bb - 8, tid); return; }
  if (bb == 16) { if (tid < D) bn_bias_block(W1, g1, beta1, mean1, v1, bnb, tid); return; }
  if (bb == 17) { if (tid < D) bn_bias_block(Wd, g2, beta2, mean2, v2, shd, tid); return; }
  int i = (bb - 18) * 256 + tid;
  if (i < e) {
    uint c = (uint)cols[i];
    float a = adj[i];
    ew1[i] = make_uint2(c, __float_as_uint(a));
    float w2 = a / (relc[rel[i]] + 1.0f);
    ew2[i] = make_uint2(c, __float_as_uint(w2));
  } else if (i == e) {
    ew1[i] = make_uint2(0u, 0u);
    ew2[i] = make_uint2(0u, 0u);
  }
}

// ---------------------------------------------------------------------------
// SpMM (CSR pull): 4 rows per wave, 16 lanes per row, one uint4 (16 B = 8
// bf16) gather per lane per edge -> one dwordx4 instruction serves 4 edges.
// Edge meta from packed ew[] (col, weight). Masked to max degree of the 4
// rows (masked slots clamp to last edge, weight 0 -> L1-hot re-read).
//   outA[r] = sum_e w_e * src[col_e]   (+ SELF: src[r]*(ck[r]+1)),  bf16 out.
//   rowsum[r] = sum_e w_e.
// ---------------------------------------------------------------------------
template <bool SELF>
__global__ __launch_bounds__(256) void spmm4_kernel(
    const ushort* __restrict__ src, const int* __restrict__ row_ptr,
    const uint2* __restrict__ ew, const float* __restrict__ ck,
    ushort* __restrict__ outA, float* __restrict__ rowsum, int n) {
  const int lane = threadIdx.x & 63;
  const int g = lane >> 4, m = lane & 15;
  const int r = blockIdx.x * 16 + (threadIdx.x >> 6) * 4 + g;
  const int rr = r < n ? r : n - 1;
  const int e0 = row_ptr[rr];
  int len = row_ptr[rr + 1] - e0;
  if (r >= n) len = 0;
  int mx = len;
  mx = max(mx, __shfl_xor(mx, 16));
  mx = max(mx, __shfl_xor(mx, 32));
  const int lastOff = len > 0 ? len - 1 : 0;

  const uint4* S4 = reinterpret_cast<const uint4*>(src);  // row stride 16
  float acc[8] = {0.f, 0.f, 0.f, 0.f, 0.f, 0.f, 0.f, 0.f};
  float ws = 0.f;

  for (int i = 0; i < mx; i += 4) {
    uint2 md[4];
    uint4 gv[4];
#pragma unroll
    for (int u = 0; u < 4; ++u) {
      int ii = i + u;
      int off = ii < len ? ii : lastOff;
      md[u] = ew[e0 + off];
    }
#pragma unroll
    for (int u = 0; u < 4; ++u) gv[u] = S4[(size_t)md[u].x * 16 + m];
#pragma unroll
    for (int u = 0; u < 4; ++u) {
      float w = (i + u) < len ? __uint_as_float(md[u].y) : 0.f;
      ws += w;
      acc[0] = fmaf(w, bflo(gv[u].x), acc[0]);
      acc[1] = fmaf(w, bfhi(gv[u].x), acc[1]);
      acc[2] = fmaf(w, bflo(gv[u].y), acc[2]);
      acc[3] = fmaf(w, bfhi(gv[u].y), acc[3]);
      acc[4] = fmaf(w, bflo(gv[u].z), acc[4]);
      acc[5] = fmaf(w, bfhi(gv[u].z), acc[5]);
      acc[6] = fmaf(w, bflo(gv[u].w), acc[6]);
      acc[7] = fmaf(w, bfhi(gv[u].w), acc[7]);
    }
  }

  if (r >= n) return;
  if (SELF) {
    uint4 us = S4[(size_t)rr * 16 + m];
    float cp = ck[rr] + 1.0f;
    acc[0] = fmaf(cp, bflo(us.x), acc[0]);
    acc[1] = fmaf(cp, bfhi(us.x), acc[1]);
    acc[2] = fmaf(cp, bflo(us.y), acc[2]);
    acc[3] = fmaf(cp, bfhi(us.y), acc[3]);
    acc[4] = fmaf(cp, bflo(us.z), acc[4]);
    acc[5] = fmaf(cp, bfhi(us.z), acc[5]);
    acc[6] = fmaf(cp, bflo(us.w), acc[6]);
    acc[7] = fmaf(cp, bfhi(us.w), acc[7]);
  }
  uint4 o;
  o.x = (uint)f2bf(acc[0]) | ((uint)f2bf(acc[1]) << 16);
  o.y = (uint)f2bf(acc[2]) | ((uint)f2bf(acc[3]) << 16);
  o.z = (uint)f2bf(acc[4]) | ((uint)f2bf(acc[5]) << 16);
  o.w = (uint)f2bf(acc[6]) | ((uint)f2bf(acc[7]) << 16);
  reinterpret_cast<uint4*>(outA)[(size_t)r * 16 + m] = o;
  if (m == 0) rowsum[r] = ws;
}

// ---------------------------------------------------------------------------
// GEMM1 (MFMA, no LDS, no barriers): y1 = tanh(A @ Ws + rs1*bnb + b1), bf16.
// ---------------------------------------------------------------------------
__global__ __launch_bounds__(256) void gemm1_mfma_kernel(
    const ushort* __restrict__ A, const ushort* __restrict__ Bf,
    const float* __restrict__ bnb, const float* __restrict__ b1,
    const float* __restrict__ rs1, ushort* __restrict__ y1, int M) {
  const int wave = threadIdx.x >> 6, lane = threadIdx.x & 63;
  const int row0 = blockIdx.x * 64 + wave * 16;
  if (row0 >= M) return;
  const int m = lane & 15, q = lane >> 4;
  const int row = row0 + m;
  const int arow = row < M ? row : M - 1;

  const bf16x8* Av = reinterpret_cast<const bf16x8*>(A);  // row stride: 16 frags
  const bf16x8* Bv = reinterpret_cast<const bf16x8*>(Bf);

  bf16x8 af[4];
#pragma unroll
  for (int kc = 0; kc < 4; ++kc) af[kc] = Av[(size_t)arow * 16 + kc * 4 + q];

  f32x4 acc[8];
#pragma unroll
  for (int nt = 0; nt < 8; ++nt) acc[nt] = (f32x4){0.f, 0.f, 0.f, 0.f};

#pragma unroll
  for (int kc = 0; kc < 4; ++kc) {
#pragma unroll
    for (int nt = 0; nt < 8; ++nt) {
      bf16x8 b = Bv[(kc * 8 + nt) * 64 + lane];
      acc[nt] = __builtin_amdgcn_mfma_f32_16x16x32_bf16(b, af[kc], acc[nt], 0, 0, 0);
    }
  }

  if (row < M) {
    float rs = rs1[row];
#pragma unroll
    for (int nt = 0; nt < 8; ++nt) {
      const float4 bn = *reinterpret_cast<const float4*>(&bnb[nt * 16 + q * 4]);
      const float4 bb = *reinterpret_cast<const float4*>(&b1[nt * 16 + q * 4]);
      ushort4 o;
      o.x = f2bf(tanhf(acc[nt][0] + rs * bn.x + bb.x));
      o.y = f2bf(tanhf(acc[nt][1] + rs * bn.y + bb.y));
      o.z = f2bf(tanhf(acc[nt][2] + rs * bn.z + bb.z));
      o.w = f2bf(tanhf(acc[nt][3] + rs * bn.w + bb.w));
      *reinterpret_cast<ushort4*>(&y1[(size_t)row * D + nt * 16 + q * 4]) = o;
    }
  }
}

// ---------------------------------------------------------------------------
// GEMM2 + finalize (fused): y2 = A2 @ Wds + (rs2+ck+1)*shd + bd, then
// out[r] = l2n([l2n(x_r), l2n(y1_r), l2n(y2_r)]).
// ---------------------------------------------------------------------------
__global__ __launch_bounds__(256) void gemm2_fused_kernel(
    const ushort* __restrict__ A2, const ushort* __restrict__ Bf,
    const float* __restrict__ shd, const float* __restrict__ bd,
    const float* __restrict__ rs2, const float* __restrict__ ck,
    const float* __restrict__ x, const ushort* __restrict__ y1,
    float* __restrict__ out, int M) {
  const int wave = threadIdx.x >> 6, lane = threadIdx.x & 63;
  const int row0 = blockIdx.x * 64 + wave * 16;
  if (row0 >= M) return;
  const int m = lane & 15, q = lane >> 4;
  const int row = row0 + m;
  const int arow = row < M ? row : M - 1;

  const bf16x8* Av = reinterpret_cast<const bf16x8*>(A2);
  const bf16x8* Bv = reinterpret_cast<const bf16x8*>(Bf);

  bf16x8 af[4];
#pragma unroll
  for (int kc = 0; kc < 4; ++kc) af[kc] = Av[(size_t)arow * 16 + kc * 4 + q];

  f32x4 acc[8];
#pragma unroll
  for (int nt = 0; nt < 8; ++nt) acc[nt] = (f32x4){0.f, 0.f, 0.f, 0.f};

#pragma unroll
  for (int kc = 0; kc < 4; ++kc) {
#pragma unroll
    for (int nt = 0; nt < 8; ++nt) {
      bf16x8 b = Bv[(kc * 8 + nt) * 64 + lane];
      acc[nt] = __builtin_amdgcn_mfma_f32_16x16x32_bf16(b, af[kc], acc[nt], 0, 0, 0);
    }
  }

  const float rb = rs2[arow] + ck[arow] + 1.0f;
  float4 xv[8];
  ushort4 y1v[8];
  float s0 = 0.f, s1 = 0.f, s2 = 0.f;
#pragma unroll
  for (int nt = 0; nt < 8; ++nt) {
    const float4 sh = *reinterpret_cast<const float4*>(&shd[nt * 16 + q * 4]);
    const float4 bb = *reinterpret_cast<const float4*>(&bd[nt * 16 + q * 4]);
    acc[nt][0] += rb * sh.x + bb.x;
    acc[nt][1] += rb * sh.y + bb.y;
    acc[nt][2] += rb * sh.z + bb.z;
    acc[nt][3] += rb * sh.w + bb.w;
    s2 += acc[nt][0] * acc[nt][0] + acc[nt][1] * acc[nt][1] +
          acc[nt][2] * acc[nt][2] + acc[nt][3] * acc[nt][3];
    xv[nt] = *reinterpret_cast<const float4*>(&x[(size_t)arow * D + nt * 16 + q * 4]);
    s0 += xv[nt].x * xv[nt].x + xv[nt].y * xv[nt].y +
          xv[nt].z * xv[nt].z + xv[nt].w * xv[nt].w;
    y1v[nt] = *reinterpret_cast<const ushort4*>(&y1[(size_t)arow * D + nt * 16 + q * 4]);
    float ya = bf2f(y1v[nt].x), yb = bf2f(y1v[nt].y);
    float yc = bf2f(y1v[nt].z), yd = bf2f(y1v[nt].w);
    s1 += ya * ya + yb * yb + yc * yc + yd * yd;
  }
  s0 += __shfl_xor(s0, 16); s0 += __shfl_xor(s0, 32);
  s1 += __shfl_xor(s1, 16); s1 += __shfl_xor(s1, 32);
  s2 += __shfl_xor(s2, 16); s2 += __shfl_xor(s2, 32);
  const float i0 = 1.0f / sqrtf(fmaxf(s0, L2_EPS));
  const float i1 = 1.0f / sqrtf(fmaxf(s1, L2_EPS));
  const float i2 = 1.0f / sqrtf(fmaxf(s2, L2_EPS));
  const float tot = s0 * i0 * i0 + s1 * i1 * i1 + s2 * i2 * i2;
  const float sc = 1.0f / sqrtf(fmaxf(tot, L2_EPS));
  const float f0 = i0 * sc, f1 = i1 * sc, f2 = i2 * sc;

  if (row < M) {
    float* orow = out + (size_t)row * 384;
#pragma unroll
    for (int nt = 0; nt < 8; ++nt) {
      const int c = nt * 16 + q * 4;
      float4 ox = make_float4(xv[nt].x * f0, xv[nt].y * f0, xv[nt].z * f0, xv[nt].w * f0);
      float4 oy = make_float4(bf2f(y1v[nt].x) * f1, bf2f(y1v[nt].y) * f1,
                              bf2f(y1v[nt].z) * f1, bf2f(y1v[nt].w) * f1);
      float4 oz = make_float4(acc[nt][0] * f2, acc[nt][1] * f2,
                              acc[nt][2] * f2, acc[nt][3] * f2);
      *reinterpret_cast<float4*>(orow + c) = ox;
      *reinterpret_cast<float4*>(orow + 128 + c) = oy;
      *reinterpret_cast<float4*>(orow + 256 + c) = oz;
    }
  }
}

// ---------------------------------------------------------------------------
extern "C" void kernel_launch(void* const* d_in, const int* in_sizes, int n_in,
                              void* d_out, int out_size, void* d_ws, size_t ws_size,
                              hipStream_t stream) {
  const float* x      = (const float*)d_in[0];
  const int*   rows   = (const int*)d_in[1];
  const int*   cols   = (const int*)d_in[2];
  const float* adj    = (const float*)d_in[3];
  const int*   rel    = (const int*)d_in[4];
  const float* gamma1 = (const float*)d_in[5];
  const float* beta1  = (const float*)d_in[6];
  const float* mean1  = (const float*)d_in[7];
  const float* var1   = (const float*)d_in[8];
  const float* W1     = (const float*)d_in[9];
  const float* b1     = (const float*)d_in[10];
  const float* gamma2 = (const float*)d_in[11];
  const float* beta2  = (const float*)d_in[12];
  const float* mean2  = (const float*)d_in[13];
  const float* var2   = (const float*)d_in[14];
  const float* relc   = (const float*)d_in[15];
  const float* ck     = (const float*)d_in[16];
  const float* Wd     = (const float*)d_in[17];
  const float* bd     = (const float*)d_in[18];
  float* out = (float*)d_out;

  const int n = in_sizes[0] / D;
  const int e = in_sizes[1];
  size_t nd = (size_t)n * D;

  char* p = (char*)d_ws;
  ushort* xbf   = (ushort*)p; p += nd * 2;
  ushort* y1bf  = (ushort*)p; p += nd * 2;
  ushort* aggbf = (ushort*)p; p += nd * 2;
  ushort* Bf1   = (ushort*)p; p += 32768;
  ushort* Bf2   = (ushort*)p; p += 32768;
  float*  bnb   = (float*)p;  p += 512;
  float*  shd   = (float*)p;  p += 512;
  float*  rs1   = (float*)p;  p += (size_t)n * 4;
  float*  rs2   = (float*)p;  p += (size_t)n * 4;
  p = (char*)(((uintptr_t)p + 15) & ~(uintptr_t)15);
  uint2* ew1    = (uint2*)p;  p += (size_t)(e + 1) * 8;
  uint2* ew2    = (uint2*)p;  p += (size_t)(e + 1) * 8;
  int* row_ptr  = (int*)p;    p += (size_t)(n + 1) * 4;

  const int n4 = (int)(nd / 4);
  const int nbConv = (n4 + 255) / 256;
  const int nbRp = (n + 1 + 255) / 256;
  const int nbEw = (e + 1 + 255) / 256;
  const int nbPrep = nbConv + nbRp + 18 + nbEw;

  prep_kernel<<<nbPrep, 256, 0, stream>>>(
      x, xbf, n4, rows, row_ptr, n, e,
      W1, gamma1, var1, Bf1, Wd, gamma2, var2, Bf2,
      beta1, mean1, bnb, beta2, mean2, shd,
      cols, adj, rel, relc, ew1, ew2, nbConv, nbRp);

  int sblocks = (n + 15) / 16;
  int gblocks = (n + 63) / 64;

  spmm4_kernel<false><<<sblocks, 256, 0, stream>>>(
      xbf, row_ptr, ew1, nullptr, aggbf, rs1, n);
  gemm1_mfma_kernel<<<gblocks, 256, 0, stream>>>(aggbf, Bf1, bnb, b1, rs1, y1bf, n);
  spmm4_kernel<true><<<sblocks, 256, 0, stream>>>(
      y1bf, row_ptr, ew2, ck, aggbf, rs2, n);
  gemm2_fused_kernel<<<gblocks, 256, 0, stream>>>(
      aggbf, Bf2, shd, bd, rs2, ck, x, y1bf, out, n);
}